// Round 5
// baseline (233.147 us; speedup 1.0000x reference)
//
#include <hip/hip_runtime.h>
#include <hip/hip_bf16.h>

#define IN_F    512
#define OUT_F   512
#define BATCH_N 1024
#define OCHUNK  32   // o-columns per wave
#define NB      4    // batches per wave (x register reuse)

typedef float f32x4 __attribute__((ext_vector_type(4)));

// ---------------------------------------------------------------------------
// Kernel 1: wstd[o,i] = exp(0.5*weight_logvar[o,i]); bstd[o] = exp(0.5*bias_logvar[o])
// ---------------------------------------------------------------------------
__global__ __launch_bounds__(256) void std_precompute_kernel(
    const float* __restrict__ wlv, const float* __restrict__ blv,
    float* __restrict__ wstd, float* __restrict__ bstd)
{
    int i = blockIdx.x * blockDim.x + threadIdx.x;      // float4 index
    f32x4 v = reinterpret_cast<const f32x4*>(wlv)[i];
    f32x4 s;
    s.x = expf(0.5f * v.x);
    s.y = expf(0.5f * v.y);
    s.z = expf(0.5f * v.z);
    s.w = expf(0.5f * v.w);
    reinterpret_cast<f32x4*>(wstd)[i] = s;
    if (blockIdx.x == 0 && threadIdx.x < OUT_F / 4) {
        f32x4 bv = reinterpret_cast<const f32x4*>(blv)[threadIdx.x];
        f32x4 bs;
        bs.x = expf(0.5f * bv.x);
        bs.y = expf(0.5f * bv.y);
        bs.z = expf(0.5f * bv.z);
        bs.w = expf(0.5f * bv.w);
        reinterpret_cast<f32x4*>(bstd)[threadIdx.x] = bs;
    }
}

// ---------------------------------------------------------------------------
// Kernel 2: block = (o-chunk c, 16-batch group). 4 waves share the o-chunk
// (mu/std L1 reuse); each wave owns NB=4 batches (x register reuse).
// Lane l owns i-slots {4l..4l+3, 256+4l..259+4l}. eps stream non-temporal.
// ---------------------------------------------------------------------------
template <bool STD_IN_WS>
__global__ __launch_bounds__(256) void bayes_main_kernel(
    const float* __restrict__ x,      // (B, I)
    const float* __restrict__ eps_w,  // (B, O, I)  -- 1 GiB, streamed once
    const float* __restrict__ eps_b,  // (B, O)
    const float* __restrict__ wmu,    // (O, I)
    const float* __restrict__ wstd_or_lv, // (O, I)
    const float* __restrict__ bmu,    // (O,)
    const float* __restrict__ bstd_or_lv, // (O,)
    float* __restrict__ out)          // (B, O)
{
    const int wid  = threadIdx.x >> 6;
    const int lane = threadIdx.x & 63;
    const int c    = blockIdx.x & 15;           // o-chunk (16 chunks of 32)
    const int bq   = blockIdx.x >> 4;           // batch group (64 groups of 16)
    const int b0   = bq * 16 + wid * NB;
    const int o0   = c * OCHUNK;

    // x[b0..b0+3, :] into registers (reused for all 32 o's)
    f32x4 xa[NB], xb[NB];
    #pragma unroll
    for (int ib = 0; ib < NB; ++ib) {
        const float* xp = x + (size_t)(b0 + ib) * IN_F;
        xa[ib] = *reinterpret_cast<const f32x4*>(xp + lane * 4);
        xb[ib] = *reinterpret_cast<const f32x4*>(xp + 256 + lane * 4);
    }

    const int q = lane >> 4;        // quarter-group = which ib this lane finalizes

    #pragma unroll 1
    for (int oo = 0; oo < OCHUNK; ++oo) {
        const int o = o0 + oo;

        // ---- HBM stream: 8 non-temporal float4 loads ----
        f32x4 ea[NB], eb[NB];
        #pragma unroll
        for (int ib = 0; ib < NB; ++ib) {
            const f32x4* ep = reinterpret_cast<const f32x4*>(
                eps_w + ((size_t)(b0 + ib) * OUT_F + o) * IN_F);
            ea[ib] = __builtin_nontemporal_load(ep + lane);
            eb[ib] = __builtin_nontemporal_load(ep + 64 + lane);
        }

        // ---- L2-resident mu/std (shared by 4 waves via L1) ----
        const f32x4 ma = *reinterpret_cast<const f32x4*>(wmu + (size_t)o * IN_F + lane * 4);
        const f32x4 mb = *reinterpret_cast<const f32x4*>(wmu + (size_t)o * IN_F + 256 + lane * 4);
        f32x4 sa = *reinterpret_cast<const f32x4*>(wstd_or_lv + (size_t)o * IN_F + lane * 4);
        f32x4 sb = *reinterpret_cast<const f32x4*>(wstd_or_lv + (size_t)o * IN_F + 256 + lane * 4);
        if (!STD_IN_WS) {
            sa.x = expf(0.5f * sa.x); sa.y = expf(0.5f * sa.y);
            sa.z = expf(0.5f * sa.z); sa.w = expf(0.5f * sa.w);
            sb.x = expf(0.5f * sb.x); sb.y = expf(0.5f * sb.y);
            sb.z = expf(0.5f * sb.z); sb.w = expf(0.5f * sb.w);
        }

        float acc[NB];
        #pragma unroll
        for (int ib = 0; ib < NB; ++ib) {
            float a;
            a = fmaf(sa.x, ea[ib].x, ma.x) * xa[ib].x;
            a = fmaf(fmaf(sa.y, ea[ib].y, ma.y), xa[ib].y, a);
            a = fmaf(fmaf(sa.z, ea[ib].z, ma.z), xa[ib].z, a);
            a = fmaf(fmaf(sa.w, ea[ib].w, ma.w), xa[ib].w, a);
            a = fmaf(fmaf(sb.x, eb[ib].x, mb.x), xb[ib].x, a);
            a = fmaf(fmaf(sb.y, eb[ib].y, mb.y), xb[ib].y, a);
            a = fmaf(fmaf(sb.z, eb[ib].z, mb.z), xb[ib].z, a);
            a = fmaf(fmaf(sb.w, eb[ib].w, mb.w), xb[ib].w, a);
            acc[ib] = a;
        }

        // ---- Reduction, selector trick: 12 DS ops instead of 24 ----
        // Levels 32,16 on all 4 chains; then each 16-lane quarter q finishes
        // chain ib=q with levels 8..1 (4-way parallel epilogue).
        #pragma unroll
        for (int ib = 0; ib < NB; ++ib) {
            acc[ib] += __shfl_xor(acc[ib], 32, 64);
            acc[ib] += __shfl_xor(acc[ib], 16, 64);
        }
        float v = q == 0 ? acc[0] : (q == 1 ? acc[1] : (q == 2 ? acc[2] : acc[3]));
        v += __shfl_xor(v, 8, 64);
        v += __shfl_xor(v, 4, 64);
        v += __shfl_xor(v, 2, 64);
        v += __shfl_xor(v, 1, 64);

        if ((lane & 15) == 0) {
            const size_t oidx = (size_t)(b0 + q) * OUT_F + o;
            const float ebv = __builtin_nontemporal_load(eps_b + oidx);
            float bs = bstd_or_lv[o];
            if (!STD_IN_WS) bs = expf(0.5f * bs);
            __builtin_nontemporal_store(v + bmu[o] + bs * ebv, out + oidx);
        }
    }
}

extern "C" void kernel_launch(void* const* d_in, const int* in_sizes, int n_in,
                              void* d_out, int out_size, void* d_ws, size_t ws_size,
                              hipStream_t stream) {
    const float* x      = (const float*)d_in[0];
    const float* eps_w  = (const float*)d_in[1];
    const float* eps_b  = (const float*)d_in[2];
    const float* wmu    = (const float*)d_in[3];
    const float* wlv    = (const float*)d_in[4];
    const float* bmu    = (const float*)d_in[5];
    const float* blv    = (const float*)d_in[6];
    float* out = (float*)d_out;

    // 1024 blocks = 64 batch-groups x 16 o-chunks -> exactly 4 blocks/CU
    const int blocks = (BATCH_N / (4 * NB)) * (OUT_F / OCHUNK);

    const size_t std_bytes = (size_t)OUT_F * IN_F * sizeof(float) + OUT_F * sizeof(float);
    if (ws_size >= std_bytes) {
        float* wstd = (float*)d_ws;
        float* bstd = wstd + (size_t)OUT_F * IN_F;
        std_precompute_kernel<<<OUT_F * IN_F / 4 / 256, 256, 0, stream>>>(wlv, blv, wstd, bstd);
        bayes_main_kernel<true><<<blocks, 256, 0, stream>>>(
            x, eps_w, eps_b, wmu, wstd, bmu, bstd, out);
    } else {
        bayes_main_kernel<false><<<blocks, 256, 0, stream>>>(
            x, eps_w, eps_b, wmu, wlv, bmu, blv, out);
    }
}

// Round 6
// 196.536 us; speedup vs baseline: 1.1863x; 1.1863x over previous
//
#include <hip/hip_runtime.h>
#include <hip/hip_bf16.h>

#define IN_F    512
#define OUT_F   512
#define BATCH_N 1024
#define OCHUNK  32   // o-columns per wave
#define NB      4    // batches per wave (mu/std register reuse)

typedef float f32x4 __attribute__((ext_vector_type(4)));

// ---------------------------------------------------------------------------
// Kernel 1: wstd[o,i] = exp(0.5*weight_logvar[o,i]); bstd[o] = exp(0.5*bias_logvar[o])
// ---------------------------------------------------------------------------
__global__ __launch_bounds__(256) void std_precompute_kernel(
    const float* __restrict__ wlv, const float* __restrict__ blv,
    float* __restrict__ wstd, float* __restrict__ bstd)
{
    int i = blockIdx.x * blockDim.x + threadIdx.x;      // float4 index
    f32x4 v = reinterpret_cast<const f32x4*>(wlv)[i];
    f32x4 s;
    s.x = expf(0.5f * v.x);
    s.y = expf(0.5f * v.y);
    s.z = expf(0.5f * v.z);
    s.w = expf(0.5f * v.w);
    reinterpret_cast<f32x4*>(wstd)[i] = s;
    if (blockIdx.x == 0 && threadIdx.x < OUT_F / 4) {
        f32x4 bv = reinterpret_cast<const f32x4*>(blv)[threadIdx.x];
        f32x4 bs;
        bs.x = expf(0.5f * bv.x);
        bs.y = expf(0.5f * bv.y);
        bs.z = expf(0.5f * bv.z);
        bs.w = expf(0.5f * bv.w);
        reinterpret_cast<f32x4*>(bstd)[threadIdx.x] = bs;
    }
}

// ---------------------------------------------------------------------------
// Kernel 2: block = (o-chunk c, 16-batch group). 4 waves share the o-chunk
// (mu/std L1 reuse); each wave owns NB=4 batches (mu/std register reuse).
// Lane l owns i-slots {4l..4l+3, 256+4l..259+4l}. eps_* loads non-temporal.
// NOTE: 24-op ILP-4 butterfly + serial lane-0 epilogue is the FAST variant;
// the "cheaper" selector-trick reduction (R5) regressed 197->233 us (serial
// DS tail exposed latency at 4 waves/SIMD). Do not "optimize" it again.
// ---------------------------------------------------------------------------
template <bool STD_IN_WS>
__global__ __launch_bounds__(256) void bayes_main_kernel(
    const float* __restrict__ x,      // (B, I)
    const float* __restrict__ eps_w,  // (B, O, I)  -- 1 GiB, streamed once
    const float* __restrict__ eps_b,  // (B, O)
    const float* __restrict__ wmu,    // (O, I)
    const float* __restrict__ wstd_or_lv, // (O, I)
    const float* __restrict__ bmu,    // (O,)
    const float* __restrict__ bstd_or_lv, // (O,): std if STD_IN_WS else logvar
    float* __restrict__ out)          // (B, O)
{
    const int wid  = threadIdx.x >> 6;
    const int lane = threadIdx.x & 63;
    const int c    = blockIdx.x & 15;           // o-chunk index (16 chunks)
    const int bq   = blockIdx.x >> 4;           // batch group (64 groups of 16)
    const int b0   = bq * 16 + wid * NB;
    const int o0   = c * OCHUNK;

    // x[b0..b0+3, :] into registers (reused for all 32 o's)
    f32x4 xa[NB], xb[NB];
    #pragma unroll
    for (int ib = 0; ib < NB; ++ib) {
        const float* xp = x + (size_t)(b0 + ib) * IN_F;
        xa[ib] = *reinterpret_cast<const f32x4*>(xp + lane * 4);
        xb[ib] = *reinterpret_cast<const f32x4*>(xp + 256 + lane * 4);
    }

    #pragma unroll 1
    for (int oo = 0; oo < OCHUNK; ++oo) {
        const int o = o0 + oo;

        // ---- HBM stream: 8 non-temporal float4 loads (evict-first) ----
        f32x4 ea[NB], eb[NB];
        #pragma unroll
        for (int ib = 0; ib < NB; ++ib) {
            const f32x4* ep = reinterpret_cast<const f32x4*>(
                eps_w + ((size_t)(b0 + ib) * OUT_F + o) * IN_F);
            ea[ib] = __builtin_nontemporal_load(ep + lane);
            eb[ib] = __builtin_nontemporal_load(ep + 64 + lane);
        }

        // ---- L2-resident mu/std (cacheable; shared by 4 waves via L1) ----
        const f32x4 ma = *reinterpret_cast<const f32x4*>(wmu + (size_t)o * IN_F + lane * 4);
        const f32x4 mb = *reinterpret_cast<const f32x4*>(wmu + (size_t)o * IN_F + 256 + lane * 4);
        f32x4 sa = *reinterpret_cast<const f32x4*>(wstd_or_lv + (size_t)o * IN_F + lane * 4);
        f32x4 sb = *reinterpret_cast<const f32x4*>(wstd_or_lv + (size_t)o * IN_F + 256 + lane * 4);
        if (!STD_IN_WS) {
            sa.x = expf(0.5f * sa.x); sa.y = expf(0.5f * sa.y);
            sa.z = expf(0.5f * sa.z); sa.w = expf(0.5f * sa.w);
            sb.x = expf(0.5f * sb.x); sb.y = expf(0.5f * sb.y);
            sb.z = expf(0.5f * sb.z); sb.w = expf(0.5f * sb.w);
        }

        float acc[NB];
        #pragma unroll
        for (int ib = 0; ib < NB; ++ib) {
            float a;
            a = fmaf(sa.x, ea[ib].x, ma.x) * xa[ib].x;
            a = fmaf(fmaf(sa.y, ea[ib].y, ma.y), xa[ib].y, a);
            a = fmaf(fmaf(sa.z, ea[ib].z, ma.z), xa[ib].z, a);
            a = fmaf(fmaf(sa.w, ea[ib].w, ma.w), xa[ib].w, a);
            a = fmaf(fmaf(sb.x, eb[ib].x, mb.x), xb[ib].x, a);
            a = fmaf(fmaf(sb.y, eb[ib].y, mb.y), xb[ib].y, a);
            a = fmaf(fmaf(sb.z, eb[ib].z, mb.z), xb[ib].z, a);
            a = fmaf(fmaf(sb.w, eb[ib].w, mb.w), xb[ib].w, a);
            acc[ib] = a;
        }

        // ---- 64-lane butterfly; 4 independent chains interleave (ILP-4) ----
        #pragma unroll
        for (int off = 32; off >= 1; off >>= 1) {
            #pragma unroll
            for (int ib = 0; ib < NB; ++ib)
                acc[ib] += __shfl_xor(acc[ib], off, 64);
        }

        if (lane == 0) {
            const float bm = bmu[o];
            float bs = bstd_or_lv[o];
            if (!STD_IN_WS) bs = expf(0.5f * bs);
            #pragma unroll
            for (int ib = 0; ib < NB; ++ib) {
                const float ebv = __builtin_nontemporal_load(
                    eps_b + (size_t)(b0 + ib) * OUT_F + o);
                out[(size_t)(b0 + ib) * OUT_F + o] = acc[ib] + bm + bs * ebv;
            }
        }
    }
}

extern "C" void kernel_launch(void* const* d_in, const int* in_sizes, int n_in,
                              void* d_out, int out_size, void* d_ws, size_t ws_size,
                              hipStream_t stream) {
    const float* x      = (const float*)d_in[0];
    const float* eps_w  = (const float*)d_in[1];
    const float* eps_b  = (const float*)d_in[2];
    const float* wmu    = (const float*)d_in[3];
    const float* wlv    = (const float*)d_in[4];
    const float* bmu    = (const float*)d_in[5];
    const float* blv    = (const float*)d_in[6];
    float* out = (float*)d_out;

    // 1024 blocks: 64 batch-groups (16 b each) x 16 o-chunks -> 4 blocks/CU
    const int blocks = (BATCH_N / (4 * NB)) * (OUT_F / OCHUNK);

    const size_t std_bytes = (size_t)OUT_F * IN_F * sizeof(float) + OUT_F * sizeof(float);
    if (ws_size >= std_bytes) {
        float* wstd = (float*)d_ws;
        float* bstd = wstd + (size_t)OUT_F * IN_F;
        std_precompute_kernel<<<OUT_F * IN_F / 4 / 256, 256, 0, stream>>>(wlv, blv, wstd, bstd);
        bayes_main_kernel<true><<<blocks, 256, 0, stream>>>(
            x, eps_w, eps_b, wmu, wstd, bmu, bstd, out);
    } else {
        bayes_main_kernel<false><<<blocks, 256, 0, stream>>>(
            x, eps_w, eps_b, wmu, wlv, bmu, blv, out);
    }
}